// Round 1
// baseline (414.060 us; speedup 1.0000x reference)
//
#include <hip/hip_runtime.h>
#include <math.h>

typedef __bf16 bf16;
typedef __bf16 bf16x8 __attribute__((ext_vector_type(8)));
typedef float f32x4 __attribute__((ext_vector_type(4)));
typedef unsigned short u16;
typedef unsigned int u32;

constexpr int BATCH = 32;
constexpr int CH    = 512;   // C
constexpr int CI    = 256;   // C/2
constexpr int NSP   = 1024;  // H*W
constexpr int OCH   = 768;   // 3*CI (theta|phi|g concat)
constexpr float EPSV = 1e-5f;

// ---------------------------------------------------------------------------
// K0a: weights -> bf16, k-blocked tiles of 64 so GEMM staging tiles are
// contiguous 16KB. wc[kt][och][64] (och: 0..255 Wt, 256..511 Wp, 512..767 Wg),
// wz[kt][cout][64] over o-dim.
// ---------------------------------------------------------------------------
__global__ void prep_weights(const float* __restrict__ Wg, const float* __restrict__ Wt,
                             const float* __restrict__ Wp, const float* __restrict__ Wz,
                             bf16* __restrict__ wc, bf16* __restrict__ wz) {
    int tid = blockIdx.x * 256 + threadIdx.x;
    if (tid < OCH * CH) {
        int r = tid / CH, c = tid % CH;
        float v;
        if (r < 256)      v = Wt[r * CH + c];
        else if (r < 512) v = Wp[(r - 256) * CH + c];
        else              v = Wg[(r - 512) * CH + c];
        wc[(size_t)(c >> 6) * (OCH * 64) + r * 64 + (c & 63)] = (bf16)v;
    } else {
        int t2 = tid - OCH * CH;
        if (t2 < CH * CI) {
            int r = t2 / CI, o = t2 % CI;
            wz[(size_t)(o >> 6) * (CH * 64) + r * 64 + (o & 63)] = (bf16)Wz[r * CI + o];
        }
    }
}

// ---------------------------------------------------------------------------
// K0b: x [b][c][n] fp32 -> xb [b][kt][n][64] bf16 (64x64 LDS transpose tiles)
// ---------------------------------------------------------------------------
__global__ void transpose_x(const float* __restrict__ x, bf16* __restrict__ xb) {
    __shared__ bf16 tile[64][64];   // [n_loc][c_loc]
    int b = blockIdx.z, kt = blockIdx.y, nb = blockIdx.x;
    int t = threadIdx.x;
    {
        int c_loc = t >> 2;           // 0..63
        int nq = t & 3;               // quarter of 16 n
        const float* src = x + ((size_t)b * CH + kt * 64 + c_loc) * NSP + nb * 64 + nq * 16;
        float vv[16];
        *(float4*)(vv + 0)  = *(const float4*)(src + 0);
        *(float4*)(vv + 4)  = *(const float4*)(src + 4);
        *(float4*)(vv + 8)  = *(const float4*)(src + 8);
        *(float4*)(vv + 12) = *(const float4*)(src + 12);
        int nbase = nq * 16;
        #pragma unroll
        for (int i = 0; i < 16; ++i) tile[nbase + i][c_loc] = (bf16)vv[i];
    }
    __syncthreads();
    {
        int n_loc = t >> 2;
        int cq = t & 3;
        bf16* dst = xb + ((((size_t)b * 8 + kt) * NSP) + nb * 64 + n_loc) * 64 + cq * 16;
        *(uint4*)(dst)     = *(const uint4*)&tile[n_loc][cq * 16];
        *(uint4*)(dst + 8) = *(const uint4*)&tile[n_loc][cq * 16 + 8];
    }
}

// ---------------------------------------------------------------------------
// K1: fused projection GEMM. D[n][och] = sum_c xb[b][n][c] * W[och][c] + bias
// theta/phi/g out in [b][n][ci] bf16 (natural layout: k=channel contiguous,
// which is what both QK^T fragments want).
// grid (6 och-tiles, 8 n-tiles, 32 b), 256 thr = 4 waves (2x2 of 64x64)
// ---------------------------------------------------------------------------
__launch_bounds__(256, 2)
__global__ void proj_gemm(const bf16* __restrict__ xb, const bf16* __restrict__ wc,
                          const float* __restrict__ bt, const float* __restrict__ bp,
                          const float* __restrict__ bg,
                          bf16* __restrict__ theta, bf16* __restrict__ phi, bf16* __restrict__ g) {
    constexpr int LDA = 72;  // 64 + 8 pad (keeps 16B align, breaks bank conflicts)
    __shared__ bf16 As[128 * LDA];
    __shared__ bf16 Bs[128 * LDA];
    int b = blockIdx.z;
    int n0 = blockIdx.y * 128;
    int oc0 = blockIdx.x * 128;
    int t = threadIdx.x, lane = t & 63, wid = t >> 6;
    int wm = wid >> 1, wn = wid & 1;
    int l15 = lane & 15, quad = lane >> 4;

    f32x4 acc[4][4] = {};
    for (int kt = 0; kt < 8; ++kt) {
        __syncthreads();
        const bf16* asrc = xb + ((((size_t)b * 8 + kt) * NSP) + n0) * 64;
        const bf16* bsrc = wc + ((size_t)kt * OCH + oc0) * 64;
        for (int s = t; s < 1024; s += 256) {
            int row = s >> 3, c8 = s & 7;
            *(uint4*)&As[row * LDA + c8 * 8] = *(const uint4*)(asrc + (size_t)s * 8);
            *(uint4*)&Bs[row * LDA + c8 * 8] = *(const uint4*)(bsrc + (size_t)s * 8);
        }
        __syncthreads();
        #pragma unroll
        for (int kc = 0; kc < 2; ++kc) {
            bf16x8 af[4], bfv[4];
            #pragma unroll
            for (int i = 0; i < 4; ++i) {
                af[i]  = *(const bf16x8*)&As[(wm * 64 + i * 16 + l15) * LDA + kc * 32 + quad * 8];
                bfv[i] = *(const bf16x8*)&Bs[(wn * 64 + i * 16 + l15) * LDA + kc * 32 + quad * 8];
            }
            #pragma unroll
            for (int i = 0; i < 4; ++i)
                #pragma unroll
                for (int j = 0; j < 4; ++j)
                    acc[i][j] = __builtin_amdgcn_mfma_f32_16x16x32_bf16(af[i], bfv[j], acc[i][j], 0, 0, 0);
        }
    }
    // epilogue: column tile of 128 lies entirely in one of theta/phi/g
    const float* bias; bf16* dst; int obase;
    if (oc0 < 256)      { bias = bt; dst = theta; obase = oc0; }
    else if (oc0 < 512) { bias = bp; dst = phi;   obase = oc0 - 256; }
    else                { bias = bg; dst = g;     obase = oc0 - 512; }
    #pragma unroll
    for (int j = 0; j < 4; ++j) {
        int och = wn * 64 + j * 16 + l15;       // 0..127
        float bv = bias[obase + och];
        #pragma unroll
        for (int i = 0; i < 4; ++i) {
            int nrow = n0 + wm * 64 + i * 16 + quad * 4;
            bf16* p = dst + ((size_t)b * NSP + nrow) * CI + obase + och;
            #pragma unroll
            for (int r = 0; r < 4; ++r)
                p[(size_t)r * CI] = (bf16)(acc[i][j][r] + bv);
        }
    }
}

// ---------------------------------------------------------------------------
// K2: fused attention. Per block: 64 q-rows (wave=16 rows), full 1024 keys.
// Two passes: (1) row-max via QK^T, (2) recompute QK^T, p=exp(s-max),
// P->LDS roundtrip (C-layout -> A-layout), O += P*V with V transposed in LDS.
// y out in k-blocked layout y[b][ot][n][64] for the output GEMM.
// ---------------------------------------------------------------------------
__launch_bounds__(256, 2)
__global__ void attn_kernel(const bf16* __restrict__ theta, const bf16* __restrict__ phi,
                            const bf16* __restrict__ g, bf16* __restrict__ y) {
    constexpr int LQ = 264;   // Q/K row stride (elems): 528B, 16B-aligned, 2-way banks
    constexpr int LV = 40;    // Vt/P row stride: 80B
    __shared__ __align__(16) char smem[42496];
    bf16* Qs = (bf16*)smem;                 // [64][LQ] staging only (aliases Ks/Vt)
    bf16* Ks = (bf16*)smem;                 // [32][LQ]  = 16896 B
    bf16* Vt = (bf16*)(smem + 16896);       // [256][LV] = 20480 B
    bf16* Pw = (bf16*)(smem + 37376);       // [4][16*LV] = 5120 B

    int b = blockIdx.y, qt = blockIdx.x;
    int t = threadIdx.x, lane = t & 63, w = t >> 6;
    int l15 = lane & 15, quad = lane >> 4;

    // stage Q = theta[b][qt*64 .. +64][256] (contiguous 32KB)
    const bf16* qsrc = theta + ((size_t)b * NSP + qt * 64) * CI;
    for (int s = t; s < 2048; s += 256) {
        int row = s >> 5, c8 = s & 31;
        *(uint4*)&Qs[row * LQ + c8 * 8] = *(const uint4*)(qsrc + (size_t)s * 8);
    }
    __syncthreads();
    bf16x8 qf[8];
    #pragma unroll
    for (int kc = 0; kc < 8; ++kc)
        qf[kc] = *(const bf16x8*)&Qs[(w * 16 + l15) * LQ + kc * 32 + quad * 8];

    const bf16* ph_b = phi + (size_t)b * NSP * CI;
    const bf16* g_b  = g + (size_t)b * NSP * CI;

    // ---- pass 1: row max ----
    float rmax[4] = {-1e30f, -1e30f, -1e30f, -1e30f};
    for (int kt = 0; kt < 32; ++kt) {
        __syncthreads();
        const bf16* ksrc = ph_b + (size_t)kt * 32 * CI;
        for (int s = t; s < 1024; s += 256) {
            int row = s >> 5, c8 = s & 31;
            *(uint4*)&Ks[row * LQ + c8 * 8] = *(const uint4*)(ksrc + (size_t)s * 8);
        }
        __syncthreads();
        #pragma unroll
        for (int h = 0; h < 2; ++h) {
            f32x4 sacc = {};
            #pragma unroll
            for (int kc = 0; kc < 8; ++kc) {
                bf16x8 kf = *(const bf16x8*)&Ks[(h * 16 + l15) * LQ + kc * 32 + quad * 8];
                sacc = __builtin_amdgcn_mfma_f32_16x16x32_bf16(qf[kc], kf, sacc, 0, 0, 0);
            }
            #pragma unroll
            for (int r = 0; r < 4; ++r) rmax[r] = fmaxf(rmax[r], sacc[r]);
        }
    }
    #pragma unroll
    for (int r = 0; r < 4; ++r)
        #pragma unroll
        for (int off = 1; off < 16; off <<= 1)
            rmax[r] = fmaxf(rmax[r], __shfl_xor(rmax[r], off, 64));

    // ---- pass 2: exp + PV ----
    f32x4 oacc[16] = {};
    float rsum[4] = {0.f, 0.f, 0.f, 0.f};
    for (int kt = 0; kt < 32; ++kt) {
        __syncthreads();
        const bf16* ksrc = ph_b + (size_t)kt * 32 * CI;
        for (int s = t; s < 1024; s += 256) {
            int row = s >> 5, c8 = s & 31;
            *(uint4*)&Ks[row * LQ + c8 * 8] = *(const uint4*)(ksrc + (size_t)s * 8);
        }
        {   // stage V transposed: Vt[o][key] = g[kt*32+key][o]
            const bf16* vsrc = g_b + (size_t)kt * 32 * CI;
            u32* vt32 = (u32*)Vt;
            #pragma unroll
            for (int ss = 0; ss < 2; ++ss) {
                int s = t + ss * 256;
                int kp = s & 15;        // key pair
                int oc = s >> 4;        // o-chunk of 8 (0..31)
                const u16* r0 = (const u16*)(vsrc + (size_t)(kp * 2) * CI + oc * 8);
                const u16* r1 = (const u16*)(vsrc + (size_t)(kp * 2 + 1) * CI + oc * 8);
                u16 a[8], c[8];
                *(uint4*)a = *(const uint4*)r0;
                *(uint4*)c = *(const uint4*)r1;
                #pragma unroll
                for (int i = 0; i < 8; ++i)
                    vt32[(oc * 8 + i) * (LV / 2) + kp] = (u32)a[i] | ((u32)c[i] << 16);
            }
        }
        __syncthreads();
        #pragma unroll
        for (int h = 0; h < 2; ++h) {
            f32x4 sacc = {};
            #pragma unroll
            for (int kc = 0; kc < 8; ++kc) {
                bf16x8 kf = *(const bf16x8*)&Ks[(h * 16 + l15) * LQ + kc * 32 + quad * 8];
                sacc = __builtin_amdgcn_mfma_f32_16x16x32_bf16(qf[kc], kf, sacc, 0, 0, 0);
            }
            #pragma unroll
            for (int r = 0; r < 4; ++r) {
                float p = __expf(sacc[r] - rmax[r]);
                rsum[r] += p;
                Pw[w * (16 * LV) + (quad * 4 + r) * LV + h * 16 + l15] = (bf16)p;
            }
        }
        __syncthreads();   // make P visible (also orders vs next staging)
        bf16x8 pf = *(const bf16x8*)&Pw[w * (16 * LV) + l15 * LV + quad * 8];
        #pragma unroll
        for (int nt = 0; nt < 16; ++nt) {
            bf16x8 vf = *(const bf16x8*)&Vt[(nt * 16 + l15) * LV + quad * 8];
            oacc[nt] = __builtin_amdgcn_mfma_f32_16x16x32_bf16(pf, vf, oacc[nt], 0, 0, 0);
        }
    }
    #pragma unroll
    for (int r = 0; r < 4; ++r)
        #pragma unroll
        for (int off = 1; off < 16; off <<= 1)
            rsum[r] += __shfl_xor(rsum[r], off, 64);
    float inv[4];
    #pragma unroll
    for (int r = 0; r < 4; ++r) inv[r] = 1.0f / rsum[r];

    int nrow = qt * 64 + w * 16 + quad * 4;
    #pragma unroll
    for (int nt = 0; nt < 16; ++nt) {
        int o = nt * 16 + l15;
        bf16* dst = y + ((((size_t)b * 4 + (o >> 6)) * NSP) + nrow) * 64 + (o & 63);
        #pragma unroll
        for (int r = 0; r < 4; ++r)
            dst[(size_t)r * 64] = (bf16)(oacc[nt][r] * inv[r]);
    }
}

// ---------------------------------------------------------------------------
// K3: output GEMM. D[cout][n] = sum_o Wz[cout][o] * y[n][o] + bz  ->
// writes w_y straight into d_out in [b][cout][n] layout (coalesced C-write).
// grid (8 n-tiles, 4 cout-tiles, 32 b)
// ---------------------------------------------------------------------------
__launch_bounds__(256, 2)
__global__ void out_gemm(const bf16* __restrict__ y, const bf16* __restrict__ wz,
                         const float* __restrict__ bz, float* __restrict__ wy) {
    constexpr int LDA = 72;
    __shared__ bf16 As[128 * LDA];
    __shared__ bf16 Bs[128 * LDA];
    int b = blockIdx.z;
    int co0 = blockIdx.y * 128;
    int n0 = blockIdx.x * 128;
    int t = threadIdx.x, lane = t & 63, wid = t >> 6;
    int wm = wid >> 1, wn = wid & 1;
    int l15 = lane & 15, quad = lane >> 4;

    f32x4 acc[4][4] = {};
    for (int kt = 0; kt < 4; ++kt) {
        __syncthreads();
        const bf16* asrc = wz + ((size_t)kt * CH + co0) * 64;
        const bf16* bsrc = y + ((((size_t)b * 4 + kt) * NSP) + n0) * 64;
        for (int s = t; s < 1024; s += 256) {
            int row = s >> 3, c8 = s & 7;
            *(uint4*)&As[row * LDA + c8 * 8] = *(const uint4*)(asrc + (size_t)s * 8);
            *(uint4*)&Bs[row * LDA + c8 * 8] = *(const uint4*)(bsrc + (size_t)s * 8);
        }
        __syncthreads();
        #pragma unroll
        for (int kc = 0; kc < 2; ++kc) {
            bf16x8 af[4], bfv[4];
            #pragma unroll
            for (int i = 0; i < 4; ++i) {
                af[i]  = *(const bf16x8*)&As[(wm * 64 + i * 16 + l15) * LDA + kc * 32 + quad * 8];
                bfv[i] = *(const bf16x8*)&Bs[(wn * 64 + i * 16 + l15) * LDA + kc * 32 + quad * 8];
            }
            #pragma unroll
            for (int i = 0; i < 4; ++i)
                #pragma unroll
                for (int j = 0; j < 4; ++j)
                    acc[i][j] = __builtin_amdgcn_mfma_f32_16x16x32_bf16(af[i], bfv[j], acc[i][j], 0, 0, 0);
        }
    }
    #pragma unroll
    for (int i = 0; i < 4; ++i) {
        int cout = co0 + wm * 64 + i * 16 + quad * 4;
        #pragma unroll
        for (int r = 0; r < 4; ++r) {
            float bv = bz[cout + r];
            #pragma unroll
            for (int j = 0; j < 4; ++j) {
                int n = n0 + wn * 64 + j * 16 + l15;
                wy[((size_t)b * CH + cout + r) * NSP + n] = acc[i][j][r] + bv;
            }
        }
    }
}

// ---------------------------------------------------------------------------
// K3b: per-channel sum/sumsq over (b, n). One block per channel.
// ---------------------------------------------------------------------------
__global__ void bn_stats(const float* __restrict__ wy, float* __restrict__ sums) {
    int ch = blockIdx.x;
    int t = threadIdx.x;
    float s = 0.f, s2 = 0.f;
    for (int b = 0; b < BATCH; ++b) {
        const float* p = wy + ((size_t)b * CH + ch) * NSP;
        for (int i = t; i < NSP; i += 256) { float v = p[i]; s += v; s2 += v * v; }
    }
    #pragma unroll
    for (int off = 1; off < 64; off <<= 1) {
        s  += __shfl_xor(s, off, 64);
        s2 += __shfl_xor(s2, off, 64);
    }
    __shared__ float ls[4], ls2[4];
    int w = t >> 6;
    if ((t & 63) == 0) { ls[w] = s; ls2[w] = s2; }
    __syncthreads();
    if (t == 0) {
        sums[ch]      = ls[0] + ls[1] + ls[2] + ls[3];
        sums[CH + ch] = ls2[0] + ls2[1] + ls2[2] + ls2[3];
    }
}

// ---------------------------------------------------------------------------
// K4: BN normalize + affine + residual, in-place on d_out. float4.
// ---------------------------------------------------------------------------
__global__ void bn_finalize(float* __restrict__ out, const float* __restrict__ x,
                            const float* __restrict__ sums,
                            const float* __restrict__ gamma, const float* __restrict__ beta) {
    size_t idx4 = (size_t)blockIdx.x * 256 + threadIdx.x;
    size_t flat = idx4 * 4;
    int ch = (int)((flat >> 10) & 511);
    float S = sums[ch], S2 = sums[CH + ch];
    const float invcnt = 1.0f / (BATCH * NSP);
    float mean = S * invcnt;
    float var = S2 * invcnt - mean * mean;
    float sc = rsqrtf(var + EPSV) * gamma[ch];
    float bi = beta[ch] - mean * sc;
    float4 wv = *(float4*)(out + flat);
    float4 xv = *(const float4*)(x + flat);
    wv.x = wv.x * sc + bi + xv.x;
    wv.y = wv.y * sc + bi + xv.y;
    wv.z = wv.z * sc + bi + xv.z;
    wv.w = wv.w * sc + bi + xv.w;
    *(float4*)(out + flat) = wv;
}

// ---------------------------------------------------------------------------
extern "C" void kernel_launch(void* const* d_in, const int* in_sizes, int n_in,
                              void* d_out, int out_size, void* d_ws, size_t ws_size,
                              hipStream_t stream) {
    const float* x     = (const float*)d_in[0];
    const float* Wg    = (const float*)d_in[1];
    const float* bg    = (const float*)d_in[2];
    const float* Wt    = (const float*)d_in[3];
    const float* bt    = (const float*)d_in[4];
    const float* Wp    = (const float*)d_in[5];
    const float* bp    = (const float*)d_in[6];
    const float* Wz    = (const float*)d_in[7];
    const float* bz    = (const float*)d_in[8];
    const float* gamma = (const float*)d_in[9];
    const float* beta  = (const float*)d_in[10];
    float* out = (float*)d_out;

    // d_ws layout (~34.6 MB)
    char* ws = (char*)d_ws;
    bf16*  y_t   = (bf16*)(ws);                   // [32][4][1024][64]  16,777,216 B
    bf16*  g_buf = (bf16*)(ws + 16777216);        // [32][1024][256]   16,777,216 B
    bf16*  wc    = (bf16*)(ws + 33554432);        // [8][768][64]         786,432 B
    bf16*  wzb   = (bf16*)(ws + 34340864);        // [4][512][64]         262,144 B
    float* sums  = (float*)(ws + 34603008);       // [2][512]               4,096 B

    // d_out doubles as scratch until out_gemm overwrites it (exact 67.1 MB fit)
    char* ob = (char*)d_out;
    bf16* xb    = (bf16*)(ob);                    // [32][8][1024][64] 33,554,432 B
    bf16* theta = (bf16*)(ob + 33554432);         // [32][1024][256]   16,777,216 B
    bf16* phi   = (bf16*)(ob + 50331648);         // [32][1024][256]   16,777,216 B

    prep_weights<<<dim3(2048), dim3(256), 0, stream>>>(Wg, Wt, Wp, Wz, wc, wzb);
    transpose_x<<<dim3(16, 8, 32), dim3(256), 0, stream>>>(x, xb);
    proj_gemm<<<dim3(6, 8, 32), dim3(256), 0, stream>>>(xb, wc, bt, bp, bg, theta, phi, g_buf);
    attn_kernel<<<dim3(16, 32), dim3(256), 0, stream>>>(theta, phi, g_buf, y_t);
    out_gemm<<<dim3(8, 4, 32), dim3(256), 0, stream>>>(y_t, wzb, bz, out);
    bn_stats<<<dim3(512), dim3(256), 0, stream>>>(out, sums);
    bn_finalize<<<dim3(16384), dim3(256), 0, stream>>>(out, x, sums, gamma, beta);
}

// Round 2
// 396.036 us; speedup vs baseline: 1.0455x; 1.0455x over previous
//
#include <hip/hip_runtime.h>
#include <math.h>

typedef __bf16 bf16;
typedef __bf16 bf16x8 __attribute__((ext_vector_type(8)));
typedef float f32x4 __attribute__((ext_vector_type(4)));
typedef unsigned short u16;
typedef unsigned int u32;

constexpr int BATCH = 32;
constexpr int CH    = 512;   // C
constexpr int CI    = 256;   // C/2
constexpr int NSP   = 1024;  // H*W
constexpr int OCH   = 768;   // 3*CI (theta|phi|g concat)
constexpr float EPSV = 1e-5f;

// ---------------------------------------------------------------------------
// K0a: weights -> bf16, k-blocked tiles of 64.
// ---------------------------------------------------------------------------
__global__ void prep_weights(const float* __restrict__ Wg, const float* __restrict__ Wt,
                             const float* __restrict__ Wp, const float* __restrict__ Wz,
                             bf16* __restrict__ wc, bf16* __restrict__ wz) {
    int tid = blockIdx.x * 256 + threadIdx.x;
    if (tid < OCH * CH) {
        int r = tid / CH, c = tid % CH;
        float v;
        if (r < 256)      v = Wt[r * CH + c];
        else if (r < 512) v = Wp[(r - 256) * CH + c];
        else              v = Wg[(r - 512) * CH + c];
        wc[(size_t)(c >> 6) * (OCH * 64) + r * 64 + (c & 63)] = (bf16)v;
    } else {
        int t2 = tid - OCH * CH;
        if (t2 < CH * CI) {
            int r = t2 / CI, o = t2 % CI;
            wz[(size_t)(o >> 6) * (CH * 64) + r * 64 + (o & 63)] = (bf16)Wz[r * CI + o];
        }
    }
}

__global__ void zero_sums(float* __restrict__ sums) {
    int t = threadIdx.x;
    #pragma unroll
    for (int i = 0; i < 4; ++i) sums[t + i * 256] = 0.0f;
}

// ---------------------------------------------------------------------------
// K0b: x [b][c][n] fp32 -> xb [b][kt][n][64] bf16 (64x64 LDS transpose tiles)
// ---------------------------------------------------------------------------
__global__ void transpose_x(const float* __restrict__ x, bf16* __restrict__ xb) {
    __shared__ bf16 tile[64][64];
    int b = blockIdx.z, kt = blockIdx.y, nb = blockIdx.x;
    int t = threadIdx.x;
    {
        int c_loc = t >> 2;
        int nq = t & 3;
        const float* src = x + ((size_t)b * CH + kt * 64 + c_loc) * NSP + nb * 64 + nq * 16;
        float vv[16];
        *(float4*)(vv + 0)  = *(const float4*)(src + 0);
        *(float4*)(vv + 4)  = *(const float4*)(src + 4);
        *(float4*)(vv + 8)  = *(const float4*)(src + 8);
        *(float4*)(vv + 12) = *(const float4*)(src + 12);
        int nbase = nq * 16;
        #pragma unroll
        for (int i = 0; i < 16; ++i) tile[nbase + i][c_loc] = (bf16)vv[i];
    }
    __syncthreads();
    {
        int n_loc = t >> 2;
        int cq = t & 3;
        bf16* dst = xb + ((((size_t)b * 8 + kt) * NSP) + nb * 64 + n_loc) * 64 + cq * 16;
        *(uint4*)(dst)     = *(const uint4*)&tile[n_loc][cq * 16];
        *(uint4*)(dst + 8) = *(const uint4*)&tile[n_loc][cq * 16 + 8];
    }
}

// ---------------------------------------------------------------------------
// K1: fused projection GEMM. theta/phi -> [b][n][ci]; g -> TRANSPOSED [b][o][n]
// (so attention can stage V without an in-LDS transpose).
// ---------------------------------------------------------------------------
__launch_bounds__(256, 2)
__global__ void proj_gemm(const bf16* __restrict__ xb, const bf16* __restrict__ wc,
                          const float* __restrict__ bt, const float* __restrict__ bp,
                          const float* __restrict__ bg,
                          bf16* __restrict__ theta, bf16* __restrict__ phi, bf16* __restrict__ gt) {
    constexpr int LDA = 72;
    __shared__ __align__(16) bf16 sm[2 * 128 * LDA];
    bf16* As = sm;
    bf16* Bs = sm + 128 * LDA;
    int b = blockIdx.z;
    int n0 = blockIdx.y * 128;
    int oc0 = blockIdx.x * 128;
    int t = threadIdx.x, lane = t & 63, wid = t >> 6;
    int wm = wid >> 1, wn = wid & 1;
    int l15 = lane & 15, quad = lane >> 4;

    f32x4 acc[4][4] = {};
    for (int kt = 0; kt < 8; ++kt) {
        __syncthreads();
        const bf16* asrc = xb + ((((size_t)b * 8 + kt) * NSP) + n0) * 64;
        const bf16* bsrc = wc + ((size_t)kt * OCH + oc0) * 64;
        for (int s = t; s < 1024; s += 256) {
            int row = s >> 3, c8 = s & 7;
            *(uint4*)&As[row * LDA + c8 * 8] = *(const uint4*)(asrc + (size_t)s * 8);
            *(uint4*)&Bs[row * LDA + c8 * 8] = *(const uint4*)(bsrc + (size_t)s * 8);
        }
        __syncthreads();
        #pragma unroll
        for (int kc = 0; kc < 2; ++kc) {
            bf16x8 af[4], bfv[4];
            #pragma unroll
            for (int i = 0; i < 4; ++i) {
                af[i]  = *(const bf16x8*)&As[(wm * 64 + i * 16 + l15) * LDA + kc * 32 + quad * 8];
                bfv[i] = *(const bf16x8*)&Bs[(wn * 64 + i * 16 + l15) * LDA + kc * 32 + quad * 8];
            }
            #pragma unroll
            for (int i = 0; i < 4; ++i)
                #pragma unroll
                for (int j = 0; j < 4; ++j)
                    acc[i][j] = __builtin_amdgcn_mfma_f32_16x16x32_bf16(af[i], bfv[j], acc[i][j], 0, 0, 0);
        }
    }
    if (oc0 < 512) {
        // theta / phi : [b][n][ci] direct scatter (32B-sector-efficient)
        const float* bias; bf16* dst; int obase;
        if (oc0 < 256) { bias = bt; dst = theta; obase = oc0; }
        else           { bias = bp; dst = phi;   obase = oc0 - 256; }
        #pragma unroll
        for (int j = 0; j < 4; ++j) {
            int och = wn * 64 + j * 16 + l15;
            float bv = bias[obase + och];
            #pragma unroll
            for (int i = 0; i < 4; ++i) {
                int nrow = n0 + wm * 64 + i * 16 + quad * 4;
                bf16* p = dst + ((size_t)b * NSP + nrow) * CI + obase + och;
                #pragma unroll
                for (int r = 0; r < 4; ++r)
                    p[(size_t)r * CI] = (bf16)(acc[i][j][r] + bv);
            }
        }
    } else {
        // g : transpose tile in LDS, write [b][o][n] coalesced
        constexpr int LT = 136;
        int obase = oc0 - 512;
        __syncthreads();              // done reading As/Bs
        bf16* T = sm;                 // 128 x LT = 17408 elems, fits in As
        #pragma unroll
        for (int j = 0; j < 4; ++j) {
            int och = wn * 64 + j * 16 + l15;
            float bv = bg[obase + och];
            #pragma unroll
            for (int i = 0; i < 4; ++i) {
                int nl = wm * 64 + i * 16 + quad * 4;
                bf16 tmp[4];
                #pragma unroll
                for (int r = 0; r < 4; ++r) tmp[r] = (bf16)(acc[i][j][r] + bv);
                *(uint2*)&T[och * LT + nl] = *(const uint2*)tmp;
            }
        }
        __syncthreads();
        for (int s = t; s < 2048; s += 256) {
            int row = s >> 4, part = s & 15;
            *(uint4*)(gt + ((size_t)b * CI + obase + row) * NSP + n0 + part * 8) =
                *(const uint4*)&T[row * LT + part * 8];
        }
    }
}

// ---------------------------------------------------------------------------
// K2: fused attention, single-pass online softmax, pipelined staging.
// 64 q-rows/block, 4 waves x 16 rows. K double-buffered; V staged from g_t
// with plain vector copies. P roundtrips LDS per-wave (no barrier needed).
// ---------------------------------------------------------------------------
__launch_bounds__(256, 2)
__global__ void attn_kernel(const bf16* __restrict__ theta, const bf16* __restrict__ phi,
                            const bf16* __restrict__ gt, bf16* __restrict__ y) {
    constexpr int LQ = 264;   // K/Q row stride: 528B (16B-aligned, 2-way banks)
    constexpr int LV = 40;    // Vt/P row stride: 80B (16B-aligned, 2-way banks)
    __shared__ __align__(16) char smem[59392];
    bf16* Ks0 = (bf16*)smem;                // [32][LQ] 16896 B
    bf16* Ks1 = (bf16*)(smem + 16896);      // 16896 B
    bf16* Vt  = (bf16*)(smem + 33792);      // [256][LV] 20480 B
    bf16* Pw  = (bf16*)(smem + 54272);      // [4][16][LV] 5120 B

    int b = blockIdx.y, qt = blockIdx.x;
    int t = threadIdx.x, lane = t & 63, w = t >> 6;
    int l15 = lane & 15, quad = lane >> 4;

    // stage Q (aliases the K double-buffer: 64*LQ*2 = 33792 B)
    bf16* Qs = (bf16*)smem;
    const bf16* qsrc = theta + ((size_t)b * NSP + qt * 64) * CI;
    for (int s = t; s < 2048; s += 256)
        *(uint4*)&Qs[(s >> 5) * LQ + (s & 31) * 8] = *(const uint4*)(qsrc + (size_t)s * 8);
    __syncthreads();
    bf16x8 qf[8];
    #pragma unroll
    for (int kc = 0; kc < 8; ++kc)
        qf[kc] = *(const bf16x8*)&Qs[(w * 16 + l15) * LQ + kc * 32 + quad * 8];
    __syncthreads();   // all Q reads done before K[0] overwrites

    const bf16* ph_b = phi + (size_t)b * NSP * CI;
    const bf16* gt_b = gt + (size_t)b * CI * NSP;

    // stage K[0]
    for (int s = t; s < 1024; s += 256)
        *(uint4*)&Ks0[(s >> 5) * LQ + (s & 31) * 8] = *(const uint4*)(ph_b + (size_t)s * 8);
    __syncthreads();

    f32x4 oacc[16] = {};
    float m[4] = {-1e30f, -1e30f, -1e30f, -1e30f};
    float ps[4] = {0.f, 0.f, 0.f, 0.f};

    for (int kt = 0; kt < 32; ++kt) {
        bf16* Kc = (kt & 1) ? Ks1 : Ks0;
        bf16* Kn = (kt & 1) ? Ks0 : Ks1;
        // (a) issue V[kt] global loads (latency hidden by QK+softmax below)
        uint4 vreg[4];
        {
            const bf16* vsrc = gt_b + kt * 32;
            #pragma unroll
            for (int ss = 0; ss < 4; ++ss) {
                int s = t + ss * 256;
                vreg[ss] = *(const uint4*)(vsrc + (size_t)(s >> 2) * NSP + (s & 3) * 8);
            }
        }
        // (b) QK^T + online softmax
        f32x4 s0 = {}, s1 = {};
        #pragma unroll
        for (int kc = 0; kc < 8; ++kc) {
            bf16x8 kf0 = *(const bf16x8*)&Kc[l15 * LQ + kc * 32 + quad * 8];
            bf16x8 kf1 = *(const bf16x8*)&Kc[(16 + l15) * LQ + kc * 32 + quad * 8];
            s0 = __builtin_amdgcn_mfma_f32_16x16x32_bf16(qf[kc], kf0, s0, 0, 0, 0);
            s1 = __builtin_amdgcn_mfma_f32_16x16x32_bf16(qf[kc], kf1, s1, 0, 0, 0);
        }
        float alpha[4];
        #pragma unroll
        for (int r = 0; r < 4; ++r) {
            float c = fmaxf(s0[r], s1[r]);
            #pragma unroll
            for (int off = 1; off < 16; off <<= 1)
                c = fmaxf(c, __shfl_xor(c, off, 16));
            float mn = fmaxf(m[r], c);
            alpha[r] = __expf(m[r] - mn);
            m[r] = mn;
            float p0 = __expf(s0[r] - mn);
            float p1 = __expf(s1[r] - mn);
            ps[r] = ps[r] * alpha[r] + p0 + p1;
            Pw[(w * 16 + quad * 4 + r) * LV + l15]      = (bf16)p0;
            Pw[(w * 16 + quad * 4 + r) * LV + 16 + l15] = (bf16)p1;
        }
        #pragma unroll
        for (int nt = 0; nt < 16; ++nt) {
            oacc[nt][0] *= alpha[0];
            oacc[nt][1] *= alpha[1];
            oacc[nt][2] *= alpha[2];
            oacc[nt][3] *= alpha[3];
        }
        // (a') V LDS writes
        #pragma unroll
        for (int ss = 0; ss < 4; ++ss) {
            int s = t + ss * 256;
            *(uint4*)&Vt[(s >> 2) * LV + (s & 3) * 8] = vreg[ss];
        }
        // (c) issue K[kt+1] global loads (latency hidden by barrier wait + PV)
        uint4 kreg[4];
        bool havek = (kt < 31);
        if (havek) {
            const bf16* ksrc = ph_b + (size_t)(kt + 1) * 32 * CI;
            #pragma unroll
            for (int ss = 0; ss < 4; ++ss)
                kreg[ss] = *(const uint4*)(ksrc + (size_t)(t + ss * 256) * 8);
        }
        __syncthreads();   // (d) Vt complete
        // (e) PV
        bf16x8 pf = *(const bf16x8*)&Pw[(w * 16 + l15) * LV + quad * 8];
        #pragma unroll
        for (int nt = 0; nt < 16; ++nt) {
            bf16x8 vf = *(const bf16x8*)&Vt[(nt * 16 + l15) * LV + quad * 8];
            oacc[nt] = __builtin_amdgcn_mfma_f32_16x16x32_bf16(pf, vf, oacc[nt], 0, 0, 0);
        }
        // (c') K[kt+1] LDS writes into other buffer
        if (havek) {
            #pragma unroll
            for (int ss = 0; ss < 4; ++ss) {
                int s = t + ss * 256;
                *(uint4*)&Kn[(s >> 5) * LQ + (s & 31) * 8] = kreg[ss];
            }
        }
        __syncthreads();   // (f) Vt reads done; Kn visible next iter
    }

    #pragma unroll
    for (int r = 0; r < 4; ++r) {
        #pragma unroll
        for (int off = 1; off < 16; off <<= 1)
            ps[r] += __shfl_xor(ps[r], off, 16);
    }
    float inv[4];
    #pragma unroll
    for (int r = 0; r < 4; ++r) inv[r] = 1.0f / ps[r];

    int nrow = qt * 64 + w * 16 + quad * 4;
    #pragma unroll
    for (int nt = 0; nt < 16; ++nt) {
        int o = nt * 16 + l15;
        bf16* dst = y + ((((size_t)b * 4 + (o >> 6)) * NSP) + nrow) * 64 + (o & 63);
        #pragma unroll
        for (int r = 0; r < 4; ++r)
            dst[(size_t)r * 64] = (bf16)(oacc[nt][r] * inv[r]);
    }
}

// ---------------------------------------------------------------------------
// K3: output GEMM + fused BN stats (shuffle-reduce + atomicAdd).
// ---------------------------------------------------------------------------
__launch_bounds__(256, 2)
__global__ void out_gemm(const bf16* __restrict__ y, const bf16* __restrict__ wz,
                         const float* __restrict__ bz, float* __restrict__ wy,
                         float* __restrict__ sums) {
    constexpr int LDA = 72;
    __shared__ __align__(16) bf16 As[128 * LDA];
    __shared__ __align__(16) bf16 Bs[128 * LDA];
    int b = blockIdx.z;
    int co0 = blockIdx.y * 128;
    int n0 = blockIdx.x * 128;
    int t = threadIdx.x, lane = t & 63, wid = t >> 6;
    int wm = wid >> 1, wn = wid & 1;
    int l15 = lane & 15, quad = lane >> 4;

    f32x4 acc[4][4] = {};
    for (int kt = 0; kt < 4; ++kt) {
        __syncthreads();
        const bf16* asrc = wz + ((size_t)kt * CH + co0) * 64;
        const bf16* bsrc = y + ((((size_t)b * 4 + kt) * NSP) + n0) * 64;
        for (int s = t; s < 1024; s += 256) {
            int row = s >> 3, c8 = s & 7;
            *(uint4*)&As[row * LDA + c8 * 8] = *(const uint4*)(asrc + (size_t)s * 8);
            *(uint4*)&Bs[row * LDA + c8 * 8] = *(const uint4*)(bsrc + (size_t)s * 8);
        }
        __syncthreads();
        #pragma unroll
        for (int kc = 0; kc < 2; ++kc) {
            bf16x8 af[4], bfv[4];
            #pragma unroll
            for (int i = 0; i < 4; ++i) {
                af[i]  = *(const bf16x8*)&As[(wm * 64 + i * 16 + l15) * LDA + kc * 32 + quad * 8];
                bfv[i] = *(const bf16x8*)&Bs[(wn * 64 + i * 16 + l15) * LDA + kc * 32 + quad * 8];
            }
            #pragma unroll
            for (int i = 0; i < 4; ++i)
                #pragma unroll
                for (int j = 0; j < 4; ++j)
                    acc[i][j] = __builtin_amdgcn_mfma_f32_16x16x32_bf16(af[i], bfv[j], acc[i][j], 0, 0, 0);
        }
    }
    #pragma unroll
    for (int i = 0; i < 4; ++i) {
        int cbase = co0 + wm * 64 + i * 16 + quad * 4;
        #pragma unroll
        for (int r = 0; r < 4; ++r) {
            int c = cbase + r;
            float bv = bz[c];
            float s = 0.f, s2 = 0.f;
            #pragma unroll
            for (int j = 0; j < 4; ++j) {
                int n = n0 + wn * 64 + j * 16 + l15;
                float v = acc[i][j][r] + bv;
                wy[((size_t)b * CH + c) * NSP + n] = v;
                s += v; s2 += v * v;
            }
            #pragma unroll
            for (int off = 1; off < 16; off <<= 1) {
                s  += __shfl_xor(s, off, 16);
                s2 += __shfl_xor(s2, off, 16);
            }
            if (l15 == 0) {
                atomicAdd(&sums[c], s);
                atomicAdd(&sums[CH + c], s2);
            }
        }
    }
}

// ---------------------------------------------------------------------------
// K4: BN normalize + affine + residual, in-place on d_out. float4.
// ---------------------------------------------------------------------------
__global__ void bn_finalize(float* __restrict__ out, const float* __restrict__ x,
                            const float* __restrict__ sums,
                            const float* __restrict__ gamma, const float* __restrict__ beta) {
    size_t idx4 = (size_t)blockIdx.x * 256 + threadIdx.x;
    size_t flat = idx4 * 4;
    int ch = (int)((flat >> 10) & 511);
    float S = sums[ch], S2 = sums[CH + ch];
    const float invcnt = 1.0f / (BATCH * NSP);
    float mean = S * invcnt;
    float var = S2 * invcnt - mean * mean;
    float sc = rsqrtf(var + EPSV) * gamma[ch];
    float bi = beta[ch] - mean * sc;
    float4 wv = *(float4*)(out + flat);
    float4 xv = *(const float4*)(x + flat);
    wv.x = wv.x * sc + bi + xv.x;
    wv.y = wv.y * sc + bi + xv.y;
    wv.z = wv.z * sc + bi + xv.z;
    wv.w = wv.w * sc + bi + xv.w;
    *(float4*)(out + flat) = wv;
}

// ---------------------------------------------------------------------------
extern "C" void kernel_launch(void* const* d_in, const int* in_sizes, int n_in,
                              void* d_out, int out_size, void* d_ws, size_t ws_size,
                              hipStream_t stream) {
    const float* x     = (const float*)d_in[0];
    const float* Wg    = (const float*)d_in[1];
    const float* bg    = (const float*)d_in[2];
    const float* Wt    = (const float*)d_in[3];
    const float* bt    = (const float*)d_in[4];
    const float* Wp    = (const float*)d_in[5];
    const float* bp    = (const float*)d_in[6];
    const float* Wz    = (const float*)d_in[7];
    const float* bz    = (const float*)d_in[8];
    const float* gamma = (const float*)d_in[9];
    const float* beta  = (const float*)d_in[10];
    float* out = (float*)d_out;

    char* ws = (char*)d_ws;
    bf16*  y_t   = (bf16*)(ws);                   // [32][4][1024][64]  16,777,216 B
    bf16*  g_t   = (bf16*)(ws + 16777216);        // [32][256][1024]   16,777,216 B
    bf16*  wc    = (bf16*)(ws + 33554432);        // [8][768][64]         786,432 B
    bf16*  wzb   = (bf16*)(ws + 34340864);        // [4][512][64]         262,144 B
    float* sums  = (float*)(ws + 34603008);       // [2][512]               4,096 B

    char* ob = (char*)d_out;                      // d_out as scratch until out_gemm
    bf16* xb    = (bf16*)(ob);                    // [32][8][1024][64] 33,554,432 B
    bf16* theta = (bf16*)(ob + 33554432);         // [32][1024][256]   16,777,216 B
    bf16* phi   = (bf16*)(ob + 50331648);         // [32][1024][256]   16,777,216 B

    prep_weights<<<dim3(2048), dim3(256), 0, stream>>>(Wg, Wt, Wp, Wz, wc, wzb);
    zero_sums<<<dim3(1), dim3(256), 0, stream>>>(sums);
    transpose_x<<<dim3(16, 8, 32), dim3(256), 0, stream>>>(x, xb);
    proj_gemm<<<dim3(6, 8, 32), dim3(256), 0, stream>>>(xb, wc, bt, bp, bg, theta, phi, g_t);
    attn_kernel<<<dim3(16, 32), dim3(256), 0, stream>>>(theta, phi, g_t, y_t);
    out_gemm<<<dim3(8, 4, 32), dim3(256), 0, stream>>>(y_t, wzb, bz, out, sums);
    bn_finalize<<<dim3(16384), dim3(256), 0, stream>>>(out, x, sums, gamma, beta);
}